// Round 17
// baseline (160.168 us; speedup 1.0000x reference)
//
#include <hip/hip_runtime.h>
#include <cstdint>
#include <cstddef>

// Block-diagonal GRU on MI355X (gfx950), fully fused bf16 MFMA path.
// B=8192, IN=1024, H=2048, NB=8, BS=256, 3H=6144.
// Round 17: R16 + correct T14 pipelining of the in-kernel h cast:
// LOADH(k) issues in body t-1's WMID (after WRITEH(k-1) consumed hf -> WAR
// safe); body t's top vmcnt(0) retires it for free; WRITEH(k) runs with no
// mid-body wait. Fixes R16's ~900cyc/body phase2 stall (164us -> ~135-140).

typedef __attribute__((ext_vector_type(8))) short bf16x8;
typedef __attribute__((ext_vector_type(4))) float f32x4;

__device__ __forceinline__ unsigned short f2bf(float f) {
    uint32_t u = __float_as_uint(f);
    u += 0x7FFFu + ((u >> 16) & 1u);   // round-to-nearest-even
    return (unsigned short)(u >> 16);
}

__device__ __forceinline__ void gload16(const void* g, void* l) {
    __builtin_amdgcn_global_load_lds(
        (const __attribute__((address_space(1))) void*)g,
        (__attribute__((address_space(3))) void*)l,
        16, 0, 0);
}

__device__ __forceinline__ float sigmoidf_(float x) {
    return 1.0f / (1.0f + __expf(-x));
}
__device__ __forceinline__ float tanhf_(float x) {
    float e = __expf(-2.0f * fabsf(x));
    float t = (1.0f - e) / (1.0f + e);
    return copysignf(t, x);
}

// ---------------------------------------------------------------- cast
// regions (float4 units): x 2097152 | W_ir 1572864 | W_h 393216  (no h)
__global__ __launch_bounds__(256)
void cast_all(const float* __restrict__ x, const float* __restrict__ wir,
              const float* __restrict__ wh,
              unsigned short* __restrict__ xb, unsigned short* __restrict__ wirb,
              unsigned short* __restrict__ whb) {
    const int i = blockIdx.x * 256 + threadIdx.x;
    const float* s; unsigned short* d; int j;
    if (i < 2097152)      { s = x;   d = xb;   j = i; }
    else if (i < 3670016) { s = wir; d = wirb; j = i - 2097152; }
    else                  { s = wh;  d = whb;  j = i - 3670016; }
    const float4 v = *reinterpret_cast<const float4*>(s + (size_t)j * 4);
    ushort4 o;
    o.x = f2bf(v.x); o.y = f2bf(v.y); o.z = f2bf(v.z); o.w = f2bf(v.w);
    *reinterpret_cast<ushort4*>(d + (size_t)j * 4) = o;
}

// ---------------------------------------------------------------- fused GRU
// acc groups: 0=r(sum), 1=z(sum), 2=wxn, 3=whn. NT = 2 (phase1) / 3 (phase2).

#define MM24(AV, BV, NT) do {                                                  \
    _Pragma("unroll")                                                          \
    for (int m_ = 0; m_ < 4; ++m_) {                                           \
        acc[0][m_][0] = __builtin_amdgcn_mfma_f32_16x16x32_bf16(               \
            AV[m_], BV[0][0], acc[0][m_][0], 0, 0, 0);                         \
        acc[0][m_][1] = __builtin_amdgcn_mfma_f32_16x16x32_bf16(               \
            AV[m_], BV[0][1], acc[0][m_][1], 0, 0, 0);                         \
        acc[1][m_][0] = __builtin_amdgcn_mfma_f32_16x16x32_bf16(               \
            AV[m_], BV[1][0], acc[1][m_][0], 0, 0, 0);                         \
        acc[1][m_][1] = __builtin_amdgcn_mfma_f32_16x16x32_bf16(               \
            AV[m_], BV[1][1], acc[1][m_][1], 0, 0, 0);                         \
        acc[NT][m_][0] = __builtin_amdgcn_mfma_f32_16x16x32_bf16(              \
            AV[m_], BV[2][0], acc[NT][m_][0], 0, 0, 0);                        \
        acc[NT][m_][1] = __builtin_amdgcn_mfma_f32_16x16x32_bf16(              \
            AV[m_], BV[2][1], acc[NT][m_][1], 0, 0, 0);                        \
    }                                                                          \
} while (0)

// fragment reads (swizzled LDS, rows 128 B); sl and offsets are literals
#define RDSET(AV, BV, sl, kbx) do {                                            \
    _Pragma("unroll")                                                          \
    for (int m_ = 0; m_ < 4; ++m_)                                             \
        AV[m_] = *(const bf16x8*)(pAr[sl] + m_ * 1024 + (kbx));                \
    _Pragma("unroll")                                                          \
    for (int s_ = 0; s_ < 3; ++s_) {                                           \
        BV[s_][0] = *(const bf16x8*)(pBr[sl] + s_ * 4096 + (kbx));             \
        BV[s_][1] = *(const bf16x8*)(pBr[sl] + s_ * 4096 + 1024 + (kbx));      \
    }                                                                          \
} while (0)

// T19 forced interleave: pull VMEM up, then alternate {2 ds_read, 5 MFMA} x 5.
#define SGB_HALF() do {                                                        \
    __builtin_amdgcn_sched_group_barrier(0x030, 5, 0);                         \
    _Pragma("unroll")                                                          \
    for (int g_ = 0; g_ < 5; ++g_) {                                           \
        __builtin_amdgcn_sched_group_barrier(0x100, 2, 0);                     \
        __builtin_amdgcn_sched_group_barrier(0x008, 5, 0);                     \
    }                                                                          \
} while (0)

// phase1 staging: 10 gloads per K-tile (unchanged from R15)
#define I_1(kt, ds) do {                                                       \
    gload16(XbB  + 0 * 32768   + (kt) * 64, As + (ds) * 8192 + 0 * 2048 + doff); \
    gload16(XbB  + 1 * 32768   + (kt) * 64, As + (ds) * 8192 + 1 * 2048 + doff); \
    gload16(XbB  + 2 * 32768   + (kt) * 64, As + (ds) * 8192 + 2 * 2048 + doff); \
    gload16(XbB  + 3 * 32768   + (kt) * 64, As + (ds) * 8192 + 3 * 2048 + doff); \
    gload16(WirB + 0 * 2097152 + 0 * 32768 + (kt) * 64, Bs + (ds) * 12288 + 0 * 2048 + doff); \
    gload16(WirB + 0 * 2097152 + 1 * 32768 + (kt) * 64, Bs + (ds) * 12288 + 1 * 2048 + doff); \
    gload16(WirB + 1 * 2097152 + 0 * 32768 + (kt) * 64, Bs + (ds) * 12288 + 2 * 2048 + doff); \
    gload16(WirB + 1 * 2097152 + 1 * 32768 + (kt) * 64, Bs + (ds) * 12288 + 3 * 2048 + doff); \
    gload16(WirB + 2 * 2097152 + 0 * 32768 + (kt) * 64, Bs + (ds) * 12288 + 4 * 2048 + doff); \
    gload16(WirB + 2 * 2097152 + 1 * 32768 + (kt) * 64, Bs + (ds) * 12288 + 5 * 2048 + doff); \
} while (0)
// phase2: B (W_h) DMA only; A (h) is reg-staged from f32
#define IB2(k2, ds) do {                                                       \
    gload16(WhB + 0 * 65536 + 0 * 8192 + (k2) * 64, Bs + (ds) * 12288 + 0 * 2048 + doff); \
    gload16(WhB + 0 * 65536 + 1 * 8192 + (k2) * 64, Bs + (ds) * 12288 + 1 * 2048 + doff); \
    gload16(WhB + 1 * 65536 + 0 * 8192 + (k2) * 64, Bs + (ds) * 12288 + 2 * 2048 + doff); \
    gload16(WhB + 1 * 65536 + 1 * 8192 + (k2) * 64, Bs + (ds) * 12288 + 3 * 2048 + doff); \
    gload16(WhB + 2 * 65536 + 0 * 8192 + (k2) * 64, Bs + (ds) * 12288 + 4 * 2048 + doff); \
    gload16(WhB + 2 * 65536 + 1 * 8192 + (k2) * 64, Bs + (ds) * 12288 + 5 * 2048 + doff); \
} while (0)
// h f32 loads (8 float4 -> regs) for phase2 A-tile k2 — ISSUED ONE BODY EARLY
#define LOADH(k2) do {                                                         \
    _Pragma("unroll") for (int q_ = 0; q_ < 4; ++q_) {                         \
        hf[q_][0] = *(const float4*)(HfB + (size_t)q_ * 32 * H + (k2) * 64);   \
        hf[q_][1] = *(const float4*)(HfB + (size_t)q_ * 32 * H + (k2) * 64 + 4); \
    }                                                                          \
} while (0)
// cvt + swizzled ds_write of the PREVIOUSLY loaded h tile into A slot ds
#define WRITEH(ds) do {                                                        \
    _Pragma("unroll") for (int q_ = 0; q_ < 4; ++q_) {                         \
        bf16x8 o_;                                                             \
        o_[0] = (short)f2bf(hf[q_][0].x); o_[1] = (short)f2bf(hf[q_][0].y);    \
        o_[2] = (short)f2bf(hf[q_][0].z); o_[3] = (short)f2bf(hf[q_][0].w);    \
        o_[4] = (short)f2bf(hf[q_][1].x); o_[5] = (short)f2bf(hf[q_][1].y);    \
        o_[6] = (short)f2bf(hf[q_][1].z); o_[7] = (short)f2bf(hf[q_][1].w);    \
        *(bf16x8*)(As + (ds) * 8192 + q_ * 2048 + wof) = o_;                   \
    }                                                                          \
} while (0)
// write old hf, THEN load next (WAR-safe in program order)
#define WH_L(ds, k2) do { WRITEH(ds); LOADH(k2); } while (0)

// Rotated body (R15) + WMID (h cvt/write + next-h load for phase2).
#define BODY(sl, STAGE, WMID, NTp, NTc) do {                                   \
    asm volatile("s_waitcnt lgkmcnt(0)" ::: "memory");                         \
    asm volatile("s_waitcnt vmcnt(0)" ::: "memory");                           \
    __builtin_amdgcn_s_barrier();                                              \
    STAGE;                                                                     \
    RDSET(avA, bvA, sl, kb0);                                                  \
    MM24(avB, bvB, NTp);                                                       \
    SGB_HALF();                                                                \
    WMID;                                                                      \
    RDSET(avB, bvB, sl, kb1);                                                  \
    MM24(avA, bvA, NTc);                                                       \
    SGB_HALF();                                                                \
    __builtin_amdgcn_sched_barrier(0);                                         \
} while (0)

__global__ __launch_bounds__(256, 2)
void gru_fused(const unsigned short* __restrict__ Xb,    // [8192][1024] bf16
               const unsigned short* __restrict__ Wirb,  // [6144][1024] bf16
               const float* __restrict__ Hf,             // [8192][2048] f32
               const unsigned short* __restrict__ Whb,   // [8][768][256] bf16
               const float* __restrict__ b_ir_lin,       // [6144]
               const float* __restrict__ b_ir,           // [6144]
               const float* __restrict__ b_hr,           // [6144]
               float* __restrict__ out) {                // [8192][2048] f32
    constexpr int K1 = 1024, H = 2048;
    __shared__ unsigned short lds[2 * 8192 + 2 * 12288];   // 80 KiB
    unsigned short* const As = lds;
    unsigned short* const Bs = lds + 2 * 8192;

    const int tid  = threadIdx.x;
    const int lane = tid & 63;
    const int w    = tid >> 6;   // 0..3
    const int wm   = w >> 1;     // 0..1 (64-row half)
    const int wn   = w & 1;      // 0..1 (32-col half)

    // Grid: 2048 = 8 kb (XCD-exclusive) x 64 bm x 4 hsub (hsub innermost).
    const int bid  = blockIdx.x;
    const int kb   = bid & 7;
    const int idx  = bid >> 3;
    const int bm   = (idx >> 2) * 128;
    const int hsub = idx & 3;
    const int hcb  = kb * 256 + hsub * 64;   // h-column base

    // ---- staging bases (phase1/B: inverse-swizzled global, linear LDS dest)
    const int srow  = tid >> 3;                 // 0..31 (row within 32-row chunk)
    const int chunk = (tid & 7) ^ (srow & 7);   // XOR involution
    const int scol  = chunk * 8;
    const int doff  = tid * 8;
    const unsigned short* XbB  = Xb   + (size_t)(bm + srow) * K1 + scol;
    const unsigned short* WirB = Wirb + (size_t)(hcb + srow) * K1 + scol;
    const unsigned short* WhB  = Whb  + (size_t)kb * 196608
                                      + (size_t)(hsub * 64 + srow) * 256 + scol;
    // phase2 A: linear f32 source (write-side swizzle instead)
    const float* HfB = Hf + (size_t)(bm + srow) * H + kb * 256 + (tid & 7) * 8;
    const int wof = (srow * 8 + ((tid & 7) ^ (srow & 7))) * 8;  // swizzled write

    // ---- fragment read bases (swizzled reads, rows are 128 B)
    const int fr  = lane & 15;
    const int k0e = (lane >> 4) * 8;
    const int mfr = (fr & 7) << 4;
    const int kb0 = ((k0e * 2) ^ mfr) >> 1;
    const int kb1 = (((k0e * 2) + 64) ^ mfr) >> 1;
    const unsigned short* pAr[2];
    const unsigned short* pBr[2];
    pAr[0] = As + (wm * 64 + fr) * 64;
    pAr[1] = As + 8192 + (wm * 64 + fr) * 64;
    pBr[0] = Bs + (wn * 32 + fr) * 64;
    pBr[1] = Bs + 12288 + (wn * 32 + fr) * 64;

    f32x4 acc[4][4][2] = {};   // [group][m-frag][n-frag]
    bf16x8 avA[4], avB[4], bvA[3][2], bvB[3][2];
    float4 hf[4][2];

    // ---- prologue: stage tile 0, then tile 1; compute tile0 kb0; defer kb1
    I_1(0, 0);
    asm volatile("s_waitcnt vmcnt(0)" ::: "memory");
    __builtin_amdgcn_s_barrier();
    I_1(1, 1);
    RDSET(avA, bvA, 0, kb0);
    RDSET(avB, bvB, 0, kb1);
    MM24(avA, bvA, 2);

    // ---- tiles 1..13 (phase1)
    BODY(1, I_1(2, 0),  ((void)0), 2, 2);
    BODY(0, I_1(3, 1),  ((void)0), 2, 2);
    BODY(1, I_1(4, 0),  ((void)0), 2, 2);
    BODY(0, I_1(5, 1),  ((void)0), 2, 2);
    BODY(1, I_1(6, 0),  ((void)0), 2, 2);
    BODY(0, I_1(7, 1),  ((void)0), 2, 2);
    BODY(1, I_1(8, 0),  ((void)0), 2, 2);
    BODY(0, I_1(9, 1),  ((void)0), 2, 2);
    BODY(1, I_1(10, 0), ((void)0), 2, 2);
    BODY(0, I_1(11, 1), ((void)0), 2, 2);
    BODY(1, I_1(12, 0), ((void)0), 2, 2);
    BODY(0, I_1(13, 1), ((void)0), 2, 2);
    BODY(1, I_1(14, 0), ((void)0), 2, 2);
    // ---- tile 14: stage last phase1 tile, pre-load h tile 0
    BODY(0, I_1(15, 1), LOADH(0),  2, 2);
    // ---- tile 15: stage B(16); write A(16)<-hf0 (no wait); load hf1
    BODY(1, IB2(0, 0),  WH_L(0, 1), 2, 2);
    // ---- tiles 16..19 (phase2)
    BODY(0, IB2(1, 1),  WH_L(1, 2), 2, 3);
    BODY(1, IB2(2, 0),  WH_L(0, 3), 3, 3);
    BODY(0, IB2(3, 1),  WRITEH(1),  3, 3);
    BODY(1, ((void)0),  ((void)0),  3, 3);
    // ---- tail: deferred kb1 of tile 19
    asm volatile("s_waitcnt lgkmcnt(0)" ::: "memory");
    MM24(avB, bvB, 3);

    // ---- gate epilogue (h read as f32)
    const int rq = (lane >> 4) * 4;
    #pragma unroll
    for (int n = 0; n < 2; ++n) {
        const int hcol = hcb + wn * 32 + n * 16 + fr;   // 0..2047
        const int lcol = hcol & 255;                    // within diagonal block
        const float bir0 = b_ir_lin[hcol]        + b_ir[hcol];
        const float bir1 = b_ir_lin[2048 + hcol] + b_ir[2048 + hcol];
        const float bir2 = b_ir_lin[4096 + hcol] + b_ir[4096 + hcol];
        const float bhr0 = b_hr[kb * 768 + lcol];
        const float bhr1 = b_hr[kb * 768 + 256 + lcol];
        const float bhr2 = b_hr[kb * 768 + 512 + lcol];
        #pragma unroll
        for (int mi = 0; mi < 4; ++mi) {
            #pragma unroll
            for (int r = 0; r < 4; ++r) {
                const int row = bm + wm * 64 + mi * 16 + rq + r;
                const float pr = acc[0][mi][n][r] + bir0 + bhr0;
                const float pz = acc[1][mi][n][r] + bir1 + bhr1;
                const float xn = acc[2][mi][n][r] + bir2;
                const float hn = acc[3][mi][n][r] + bhr2;
                const float rg = sigmoidf_(pr);
                const float zg = sigmoidf_(pz);
                const float ng = tanhf_(xn + rg * hn);
                const float hv = Hf[(size_t)row * H + hcol];
                out[(size_t)row * H + hcol] = (1.0f - zg) * hv + zg * ng;
            }
        }
    }
}

// ---------------------------------------------------------------- launch
extern "C" void kernel_launch(void* const* d_in, const int* in_sizes, int n_in,
                              void* d_out, int out_size, void* d_ws, size_t ws_size,
                              hipStream_t stream) {
    const float* x        = (const float*)d_in[0];
    const float* h        = (const float*)d_in[1];
    const float* W_ir     = (const float*)d_in[2];
    const float* b_ir_lin = (const float*)d_in[3];
    const float* b_ir     = (const float*)d_in[4];
    const float* W_h      = (const float*)d_in[5];
    const float* b_hr     = (const float*)d_in[6];
    float* out = (float*)d_out;

    char* ws = (char*)d_ws;
    unsigned short* xb   = (unsigned short*)(ws);               // 16 MiB
    unsigned short* wirb = (unsigned short*)(ws + 16777216);    // 12 MiB
    unsigned short* whb  = (unsigned short*)(ws + 29360128);    //  3 MiB

    cast_all<<<15872, 256, 0, stream>>>(x, W_ir, W_h, xb, wirb, whb);

    gru_fused<<<2048, 256, 0, stream>>>(xb, wirb, h, whb,
                                        b_ir_lin, b_ir, b_hr, out);
}

// Round 18
// 156.155 us; speedup vs baseline: 1.0257x; 1.0257x over previous
//
#include <hip/hip_runtime.h>
#include <cstdint>
#include <cstddef>

// Block-diagonal GRU on MI355X (gfx950), fully fused bf16 MFMA path.
// B=8192, IN=1024, H=2048, NB=8, BS=256, 3H=6144.
// Round 18: R15's GEMM schedule restored EXACTLY for phase1 (SGB mask 0x010,
// no mid-body fences) + h-cast elimination kept, with phase2's reg-staging
// work (WRITEH/LOADH) QUARANTINED in sched_barrier(0)-fenced WMID regions
// (BODY2) so it cannot contaminate the counted SGB groups.

typedef __attribute__((ext_vector_type(8))) short bf16x8;
typedef __attribute__((ext_vector_type(4))) float f32x4;

__device__ __forceinline__ unsigned short f2bf(float f) {
    uint32_t u = __float_as_uint(f);
    u += 0x7FFFu + ((u >> 16) & 1u);   // round-to-nearest-even
    return (unsigned short)(u >> 16);
}

__device__ __forceinline__ void gload16(const void* g, void* l) {
    __builtin_amdgcn_global_load_lds(
        (const __attribute__((address_space(1))) void*)g,
        (__attribute__((address_space(3))) void*)l,
        16, 0, 0);
}

__device__ __forceinline__ float sigmoidf_(float x) {
    return 1.0f / (1.0f + __expf(-x));
}
__device__ __forceinline__ float tanhf_(float x) {
    float e = __expf(-2.0f * fabsf(x));
    float t = (1.0f - e) / (1.0f + e);
    return copysignf(t, x);
}

// ---------------------------------------------------------------- cast
// regions (float4 units): x 2097152 | W_ir 1572864 | W_h 393216  (no h)
__global__ __launch_bounds__(256)
void cast_all(const float* __restrict__ x, const float* __restrict__ wir,
              const float* __restrict__ wh,
              unsigned short* __restrict__ xb, unsigned short* __restrict__ wirb,
              unsigned short* __restrict__ whb) {
    const int i = blockIdx.x * 256 + threadIdx.x;
    const float* s; unsigned short* d; int j;
    if (i < 2097152)      { s = x;   d = xb;   j = i; }
    else if (i < 3670016) { s = wir; d = wirb; j = i - 2097152; }
    else                  { s = wh;  d = whb;  j = i - 3670016; }
    const float4 v = *reinterpret_cast<const float4*>(s + (size_t)j * 4);
    ushort4 o;
    o.x = f2bf(v.x); o.y = f2bf(v.y); o.z = f2bf(v.z); o.w = f2bf(v.w);
    *reinterpret_cast<ushort4*>(d + (size_t)j * 4) = o;
}

// ---------------------------------------------------------------- fused GRU
// acc groups: 0=r(sum), 1=z(sum), 2=wxn, 3=whn. NT = 2 (phase1) / 3 (phase2).

#define MM24(AV, BV, NT) do {                                                  \
    _Pragma("unroll")                                                          \
    for (int m_ = 0; m_ < 4; ++m_) {                                           \
        acc[0][m_][0] = __builtin_amdgcn_mfma_f32_16x16x32_bf16(               \
            AV[m_], BV[0][0], acc[0][m_][0], 0, 0, 0);                         \
        acc[0][m_][1] = __builtin_amdgcn_mfma_f32_16x16x32_bf16(               \
            AV[m_], BV[0][1], acc[0][m_][1], 0, 0, 0);                         \
        acc[1][m_][0] = __builtin_amdgcn_mfma_f32_16x16x32_bf16(               \
            AV[m_], BV[1][0], acc[1][m_][0], 0, 0, 0);                         \
        acc[1][m_][1] = __builtin_amdgcn_mfma_f32_16x16x32_bf16(               \
            AV[m_], BV[1][1], acc[1][m_][1], 0, 0, 0);                         \
        acc[NT][m_][0] = __builtin_amdgcn_mfma_f32_16x16x32_bf16(              \
            AV[m_], BV[2][0], acc[NT][m_][0], 0, 0, 0);                        \
        acc[NT][m_][1] = __builtin_amdgcn_mfma_f32_16x16x32_bf16(              \
            AV[m_], BV[2][1], acc[NT][m_][1], 0, 0, 0);                        \
    }                                                                          \
} while (0)

// fragment reads (swizzled LDS, rows 128 B); sl and offsets are literals
#define RDSET(AV, BV, sl, kbx) do {                                            \
    _Pragma("unroll")                                                          \
    for (int m_ = 0; m_ < 4; ++m_)                                             \
        AV[m_] = *(const bf16x8*)(pAr[sl] + m_ * 1024 + (kbx));                \
    _Pragma("unroll")                                                          \
    for (int s_ = 0; s_ < 3; ++s_) {                                           \
        BV[s_][0] = *(const bf16x8*)(pBr[sl] + s_ * 4096 + (kbx));             \
        BV[s_][1] = *(const bf16x8*)(pBr[sl] + s_ * 4096 + 1024 + (kbx));      \
    }                                                                          \
} while (0)

// T19 forced interleave (R15-exact): {VMEM x5, (DS_READ x2, MFMA x5) x5}
#define SGB_HALF() do {                                                        \
    __builtin_amdgcn_sched_group_barrier(0x010, 5, 0);                         \
    _Pragma("unroll")                                                          \
    for (int g_ = 0; g_ < 5; ++g_) {                                           \
        __builtin_amdgcn_sched_group_barrier(0x100, 2, 0);                     \
        __builtin_amdgcn_sched_group_barrier(0x008, 5, 0);                     \
    }                                                                          \
} while (0)

// phase1 staging: 10 gloads per K-tile (R15-exact)
#define I_1(kt, ds) do {                                                       \
    gload16(XbB  + 0 * 32768   + (kt) * 64, As + (ds) * 8192 + 0 * 2048 + doff); \
    gload16(XbB  + 1 * 32768   + (kt) * 64, As + (ds) * 8192 + 1 * 2048 + doff); \
    gload16(XbB  + 2 * 32768   + (kt) * 64, As + (ds) * 8192 + 2 * 2048 + doff); \
    gload16(XbB  + 3 * 32768   + (kt) * 64, As + (ds) * 8192 + 3 * 2048 + doff); \
    gload16(WirB + 0 * 2097152 + 0 * 32768 + (kt) * 64, Bs + (ds) * 12288 + 0 * 2048 + doff); \
    gload16(WirB + 0 * 2097152 + 1 * 32768 + (kt) * 64, Bs + (ds) * 12288 + 1 * 2048 + doff); \
    gload16(WirB + 1 * 2097152 + 0 * 32768 + (kt) * 64, Bs + (ds) * 12288 + 2 * 2048 + doff); \
    gload16(WirB + 1 * 2097152 + 1 * 32768 + (kt) * 64, Bs + (ds) * 12288 + 3 * 2048 + doff); \
    gload16(WirB + 2 * 2097152 + 0 * 32768 + (kt) * 64, Bs + (ds) * 12288 + 4 * 2048 + doff); \
    gload16(WirB + 2 * 2097152 + 1 * 32768 + (kt) * 64, Bs + (ds) * 12288 + 5 * 2048 + doff); \
} while (0)
// phase2: B (W_h) DMA only; A (h) is reg-staged from f32
#define IB2(k2, ds) do {                                                       \
    gload16(WhB + 0 * 65536 + 0 * 8192 + (k2) * 64, Bs + (ds) * 12288 + 0 * 2048 + doff); \
    gload16(WhB + 0 * 65536 + 1 * 8192 + (k2) * 64, Bs + (ds) * 12288 + 1 * 2048 + doff); \
    gload16(WhB + 1 * 65536 + 0 * 8192 + (k2) * 64, Bs + (ds) * 12288 + 2 * 2048 + doff); \
    gload16(WhB + 1 * 65536 + 1 * 8192 + (k2) * 64, Bs + (ds) * 12288 + 3 * 2048 + doff); \
    gload16(WhB + 2 * 65536 + 0 * 8192 + (k2) * 64, Bs + (ds) * 12288 + 4 * 2048 + doff); \
    gload16(WhB + 2 * 65536 + 1 * 8192 + (k2) * 64, Bs + (ds) * 12288 + 5 * 2048 + doff); \
} while (0)
// h f32 loads (8 float4 -> regs) for phase2 A-tile k2 — issued one body early
#define LOADH(k2) do {                                                         \
    _Pragma("unroll") for (int q_ = 0; q_ < 4; ++q_) {                         \
        hf[q_][0] = *(const float4*)(HfB + (size_t)q_ * 32 * H + (k2) * 64);   \
        hf[q_][1] = *(const float4*)(HfB + (size_t)q_ * 32 * H + (k2) * 64 + 4); \
    }                                                                          \
} while (0)
// cvt + swizzled ds_write of the PREVIOUSLY loaded h tile into A slot ds
#define WRITEH(ds) do {                                                        \
    _Pragma("unroll") for (int q_ = 0; q_ < 4; ++q_) {                         \
        bf16x8 o_;                                                             \
        o_[0] = (short)f2bf(hf[q_][0].x); o_[1] = (short)f2bf(hf[q_][0].y);    \
        o_[2] = (short)f2bf(hf[q_][0].z); o_[3] = (short)f2bf(hf[q_][0].w);    \
        o_[4] = (short)f2bf(hf[q_][1].x); o_[5] = (short)f2bf(hf[q_][1].y);    \
        o_[6] = (short)f2bf(hf[q_][1].z); o_[7] = (short)f2bf(hf[q_][1].w);    \
        *(bf16x8*)(As + (ds) * 8192 + q_ * 2048 + wof) = o_;                   \
    }                                                                          \
} while (0)
// write old hf, THEN load next (WAR-safe in program order)
#define WH_L(ds, k2) do { WRITEH(ds); LOADH(k2); } while (0)

// Phase1 body: R15-exact (no mid-body fence, empty WMID).
#define BODY(sl, STAGE, NTp, NTc) do {                                         \
    asm volatile("s_waitcnt lgkmcnt(0)" ::: "memory");                         \
    asm volatile("s_waitcnt vmcnt(0)" ::: "memory");                           \
    __builtin_amdgcn_s_barrier();                                              \
    STAGE;                                                                     \
    RDSET(avA, bvA, sl, kb0);                                                  \
    MM24(avB, bvB, NTp);                                                       \
    SGB_HALF();                                                                \
    RDSET(avB, bvB, sl, kb1);                                                  \
    MM24(avA, bvA, NTc);                                                       \
    SGB_HALF();                                                                \
    __builtin_amdgcn_sched_barrier(0);                                         \
} while (0)

// Phase2/transition body: WMID quarantined between sched_barrier(0) fences
// so h-loads/cvts/ds_writes cannot be absorbed by the counted SGB groups.
#define BODY2(sl, STAGE, WMID, NTp, NTc) do {                                  \
    asm volatile("s_waitcnt lgkmcnt(0)" ::: "memory");                         \
    asm volatile("s_waitcnt vmcnt(0)" ::: "memory");                           \
    __builtin_amdgcn_s_barrier();                                              \
    STAGE;                                                                     \
    RDSET(avA, bvA, sl, kb0);                                                  \
    MM24(avB, bvB, NTp);                                                       \
    SGB_HALF();                                                                \
    __builtin_amdgcn_sched_barrier(0);                                         \
    WMID;                                                                      \
    __builtin_amdgcn_sched_barrier(0);                                         \
    RDSET(avB, bvB, sl, kb1);                                                  \
    MM24(avA, bvA, NTc);                                                       \
    SGB_HALF();                                                                \
    __builtin_amdgcn_sched_barrier(0);                                         \
} while (0)

__global__ __launch_bounds__(256, 2)
void gru_fused(const unsigned short* __restrict__ Xb,    // [8192][1024] bf16
               const unsigned short* __restrict__ Wirb,  // [6144][1024] bf16
               const float* __restrict__ Hf,             // [8192][2048] f32
               const unsigned short* __restrict__ Whb,   // [8][768][256] bf16
               const float* __restrict__ b_ir_lin,       // [6144]
               const float* __restrict__ b_ir,           // [6144]
               const float* __restrict__ b_hr,           // [6144]
               float* __restrict__ out) {                // [8192][2048] f32
    constexpr int K1 = 1024, H = 2048;
    __shared__ unsigned short lds[2 * 8192 + 2 * 12288];   // 80 KiB
    unsigned short* const As = lds;
    unsigned short* const Bs = lds + 2 * 8192;

    const int tid  = threadIdx.x;
    const int lane = tid & 63;
    const int w    = tid >> 6;   // 0..3
    const int wm   = w >> 1;     // 0..1 (64-row half)
    const int wn   = w & 1;      // 0..1 (32-col half)

    // Grid: 2048 = 8 kb (XCD-exclusive) x 64 bm x 4 hsub (hsub innermost).
    const int bid  = blockIdx.x;
    const int kb   = bid & 7;
    const int idx  = bid >> 3;
    const int bm   = (idx >> 2) * 128;
    const int hsub = idx & 3;
    const int hcb  = kb * 256 + hsub * 64;   // h-column base

    // ---- staging bases (phase1/B: inverse-swizzled global, linear LDS dest)
    const int srow  = tid >> 3;                 // 0..31 (row within 32-row chunk)
    const int chunk = (tid & 7) ^ (srow & 7);   // XOR involution
    const int scol  = chunk * 8;
    const int doff  = tid * 8;
    const unsigned short* XbB  = Xb   + (size_t)(bm + srow) * K1 + scol;
    const unsigned short* WirB = Wirb + (size_t)(hcb + srow) * K1 + scol;
    const unsigned short* WhB  = Whb  + (size_t)kb * 196608
                                      + (size_t)(hsub * 64 + srow) * 256 + scol;
    // phase2 A: linear f32 source (write-side swizzle instead)
    const float* HfB = Hf + (size_t)(bm + srow) * H + kb * 256 + (tid & 7) * 8;
    const int wof = (srow * 8 + ((tid & 7) ^ (srow & 7))) * 8;  // swizzled write

    // ---- fragment read bases (swizzled reads, rows are 128 B)
    const int fr  = lane & 15;
    const int k0e = (lane >> 4) * 8;
    const int mfr = (fr & 7) << 4;
    const int kb0 = ((k0e * 2) ^ mfr) >> 1;
    const int kb1 = (((k0e * 2) + 64) ^ mfr) >> 1;
    const unsigned short* pAr[2];
    const unsigned short* pBr[2];
    pAr[0] = As + (wm * 64 + fr) * 64;
    pAr[1] = As + 8192 + (wm * 64 + fr) * 64;
    pBr[0] = Bs + (wn * 32 + fr) * 64;
    pBr[1] = Bs + 12288 + (wn * 32 + fr) * 64;

    f32x4 acc[4][4][2] = {};   // [group][m-frag][n-frag]
    bf16x8 avA[4], avB[4], bvA[3][2], bvB[3][2];
    float4 hf[4][2];

    // ---- prologue: stage tile 0, then tile 1; compute tile0 kb0; defer kb1
    I_1(0, 0);
    asm volatile("s_waitcnt vmcnt(0)" ::: "memory");
    __builtin_amdgcn_s_barrier();
    I_1(1, 1);
    RDSET(avA, bvA, 0, kb0);
    RDSET(avB, bvB, 0, kb1);
    MM24(avA, bvA, 2);

    // ---- tiles 1..13 (phase1, R15-exact bodies)
    BODY(1, I_1(2, 0),  2, 2);
    BODY(0, I_1(3, 1),  2, 2);
    BODY(1, I_1(4, 0),  2, 2);
    BODY(0, I_1(5, 1),  2, 2);
    BODY(1, I_1(6, 0),  2, 2);
    BODY(0, I_1(7, 1),  2, 2);
    BODY(1, I_1(8, 0),  2, 2);
    BODY(0, I_1(9, 1),  2, 2);
    BODY(1, I_1(10, 0), 2, 2);
    BODY(0, I_1(11, 1), 2, 2);
    BODY(1, I_1(12, 0), 2, 2);
    BODY(0, I_1(13, 1), 2, 2);
    BODY(1, I_1(14, 0), 2, 2);
    // ---- tile 14: stage last phase1 tile, pre-load h tile 0 (fenced)
    BODY2(0, I_1(15, 1), LOADH(0),  2, 2);
    // ---- tile 15: stage B(16); write A(16)<-hf0; load hf1
    BODY2(1, IB2(0, 0),  WH_L(0, 1), 2, 2);
    // ---- tiles 16..19 (phase2)
    BODY2(0, IB2(1, 1),  WH_L(1, 2), 2, 3);
    BODY2(1, IB2(2, 0),  WH_L(0, 3), 3, 3);
    BODY2(0, IB2(3, 1),  WRITEH(1),  3, 3);
    BODY(1, ((void)0),  3, 3);
    // ---- tail: deferred kb1 of tile 19
    asm volatile("s_waitcnt lgkmcnt(0)" ::: "memory");
    MM24(avB, bvB, 3);

    // ---- gate epilogue (h read as f32)
    const int rq = (lane >> 4) * 4;
    #pragma unroll
    for (int n = 0; n < 2; ++n) {
        const int hcol = hcb + wn * 32 + n * 16 + fr;   // 0..2047
        const int lcol = hcol & 255;                    // within diagonal block
        const float bir0 = b_ir_lin[hcol]        + b_ir[hcol];
        const float bir1 = b_ir_lin[2048 + hcol] + b_ir[2048 + hcol];
        const float bir2 = b_ir_lin[4096 + hcol] + b_ir[4096 + hcol];
        const float bhr0 = b_hr[kb * 768 + lcol];
        const float bhr1 = b_hr[kb * 768 + 256 + lcol];
        const float bhr2 = b_hr[kb * 768 + 512 + lcol];
        #pragma unroll
        for (int mi = 0; mi < 4; ++mi) {
            #pragma unroll
            for (int r = 0; r < 4; ++r) {
                const int row = bm + wm * 64 + mi * 16 + rq + r;
                const float pr = acc[0][mi][n][r] + bir0 + bhr0;
                const float pz = acc[1][mi][n][r] + bir1 + bhr1;
                const float xn = acc[2][mi][n][r] + bir2;
                const float hn = acc[3][mi][n][r] + bhr2;
                const float rg = sigmoidf_(pr);
                const float zg = sigmoidf_(pz);
                const float ng = tanhf_(xn + rg * hn);
                const float hv = Hf[(size_t)row * H + hcol];
                out[(size_t)row * H + hcol] = (1.0f - zg) * hv + zg * ng;
            }
        }
    }
}

// ---------------------------------------------------------------- launch
extern "C" void kernel_launch(void* const* d_in, const int* in_sizes, int n_in,
                              void* d_out, int out_size, void* d_ws, size_t ws_size,
                              hipStream_t stream) {
    const float* x        = (const float*)d_in[0];
    const float* h        = (const float*)d_in[1];
    const float* W_ir     = (const float*)d_in[2];
    const float* b_ir_lin = (const float*)d_in[3];
    const float* b_ir     = (const float*)d_in[4];
    const float* W_h      = (const float*)d_in[5];
    const float* b_hr     = (const float*)d_in[6];
    float* out = (float*)d_out;

    char* ws = (char*)d_ws;
    unsigned short* xb   = (unsigned short*)(ws);               // 16 MiB
    unsigned short* wirb = (unsigned short*)(ws + 16777216);    // 12 MiB
    unsigned short* whb  = (unsigned short*)(ws + 29360128);    //  3 MiB

    cast_all<<<15872, 256, 0, stream>>>(x, W_ir, W_h, xb, wirb, whb);

    gru_fused<<<2048, 256, 0, stream>>>(xb, wirb, h, whb,
                                        b_ir_lin, b_ir, b_hr, out);
}